// Round 16
// baseline (1043.720 us; speedup 1.0000x reference)
//
#include <hip/hip_runtime.h>

// ===========================================================================
// conv1: 3->64, 128x128 in, pooled 63x63.
// ===========================================================================
__global__ __launch_bounds__(256)
void conv1_lds(const float* __restrict__ in, const float* __restrict__ wt,
               const float* __restrict__ bias, float* __restrict__ out)
{
    __shared__ float sh[3][34][34];
    int bx = blockIdx.x;
    int tile = bx & 15;
    int cg   = (bx >> 4) & 7;
    int b    = bx >> 7;
    int tr = tile >> 2, tc = tile & 3;
    int tid = threadIdx.x;
    int ty = tid >> 4, tx = tid & 15;
    int R0 = 32 * tr, C0 = 32 * tc;

    for (int t = tid; t < 3 * 34 * 34; t += 256) {
        int ci = t / 1156;
        int rem = t - ci * 1156;
        int rr = rem / 34, cc = rem - rr * 34;
        int gr = R0 + rr; if (gr > 127) gr = 127;
        int gc = C0 + cc; if (gc > 127) gc = 127;
        sh[ci][rr][cc] = in[(((size_t)b * 3 + ci) * 128 + gr) * 128 + gc];
    }
    __syncthreads();

    float acc[8][2][2] = {};
    int co0 = cg * 8;
#pragma unroll
    for (int ci = 0; ci < 3; ++ci) {
        float p[4][4];
#pragma unroll
        for (int r = 0; r < 4; ++r) {
            const float2* pr = reinterpret_cast<const float2*>(&sh[ci][2 * ty + r][2 * tx]);
            float2 a = pr[0], c2 = pr[1];
            p[r][0] = a.x; p[r][1] = a.y; p[r][2] = c2.x; p[r][3] = c2.y;
        }
#pragma unroll
        for (int j = 0; j < 8; ++j) {
            const float* wj = wt + ((size_t)(co0 + j) * 3 + ci) * 9;
#pragma unroll
            for (int kh = 0; kh < 3; ++kh)
#pragma unroll
                for (int kw = 0; kw < 3; ++kw) {
                    float wv = wj[kh * 3 + kw];
#pragma unroll
                    for (int dy = 0; dy < 2; ++dy)
#pragma unroll
                        for (int dx = 0; dx < 2; ++dx)
                            acc[j][dy][dx] = fmaf(wv, p[dy + kh][dx + kw], acc[j][dy][dx]);
                }
        }
    }
    int py = 16 * tr + ty, px = 16 * tc + tx;
    if (py < 63 && px < 63) {
#pragma unroll
        for (int j = 0; j < 8; ++j) {
            float v = fmaxf(fmaxf(acc[j][0][0], acc[j][0][1]),
                            fmaxf(acc[j][1][0], acc[j][1][1])) + bias[co0 + j];
            out[(((size_t)b * 64 + co0 + j) * 63 + py) * 63 + px] = fmaxf(v, 0.f);
        }
    }
}

// ===========================================================================
// conv_v9 (conv2): CO=2 per thread, 0.54 LDS B/FMA, one barrier per ci.
// ===========================================================================
template<int CIN, int DIM, int POOL, int COUT, int TILES_R, int TILES_C>
__global__ __launch_bounds__(256)
void conv_v9(const float* __restrict__ in, const float* __restrict__ wt,
             const float* __restrict__ bias, float* __restrict__ out)
{
    __shared__ __align__(16) float in_sh[2][648];   // [buf][18*36]
    __shared__ __align__(16) float w_sh[2][384];    // [buf][32 co * 12]

    constexpr int NT  = TILES_R * TILES_C;
    constexpr int NCG = COUT / 32;
    int bx = blockIdx.x;
    int tile = bx % NT;
    int cg   = (bx / NT) % NCG;
    int b    = bx / (NT * NCG);
    int rt = tile / TILES_C, ct = tile % TILES_C;
    int tid = threadIdx.x;
    int co_l = tid & 15;
    int sp   = tid >> 4;
    int ty = sp >> 2, tx = sp & 3;
    int R0 = 16 * rt, C0 = 32 * ct;

    int gofs[3], lofs[3];
#pragma unroll
    for (int j = 0; j < 3; ++j) {
        int t = tid + 256 * j; if (t > 611) t = 611;
        int rr = t / 34, cc = t - rr * 34;
        int gr = R0 + rr; if (gr > DIM - 1) gr = DIM - 1;
        int gc = C0 + cc; if (gc > DIM - 1) gc = DIM - 1;
        gofs[j] = gr * DIM + gc;
        lofs[j] = rr * 36 + cc;
    }
    int wgofs[2], wlofs[2];
#pragma unroll
    for (int j = 0; j < 2; ++j) {
        int t = tid + 256 * j; if (t > 287) t = 287;
        int c = t / 9, k = t - c * 9;
        wgofs[j] = (cg * 32 + c) * CIN * 9 + k;
        wlofs[j] = c * 12 + k;
    }
    bool wv1 = (tid < 32);

    const float* gci = in + (size_t)b * CIN * DIM * DIM;
    const float* wci = wt;

    float acc[2][4][8] = {};
    float sr[3], wr[2];

#pragma unroll
    for (int j = 0; j < 3; ++j) sr[j] = gci[gofs[j]];
    wr[0] = wci[wgofs[0]];
    wr[1] = wci[wgofs[1]];
#pragma unroll
    for (int j = 0; j < 3; ++j) { int t = tid + 256 * j; if (t < 612) in_sh[0][lofs[j]] = sr[j]; }
    w_sh[0][wlofs[0]] = wr[0];
    if (wv1) w_sh[0][wlofs[1]] = wr[1];
    __syncthreads();

    for (int ci = 0; ci < CIN; ++ci) {
        int p = ci & 1;
        if (ci < CIN - 1) {
            const float* gn = gci + (size_t)(ci + 1) * DIM * DIM;
            const float* wn = wci + (size_t)(ci + 1) * 9;
#pragma unroll
            for (int j = 0; j < 3; ++j) sr[j] = gn[gofs[j]];
            wr[0] = wn[wgofs[0]];
            wr[1] = wn[wgofs[1]];
        }
        float w[2][9];
#pragma unroll
        for (int h = 0; h < 2; ++h)
#pragma unroll
            for (int k = 0; k < 9; ++k)
                w[h][k] = w_sh[p][(co_l + 16 * h) * 12 + k];
        const float* rb = in_sh[p] + 8 * tx;
#pragma unroll
        for (int r = 0; r < 6; ++r) {
            const float* rp = rb + (4 * ty + r) * 36;
            float4 a = *reinterpret_cast<const float4*>(rp);
            float4 b4 = *reinterpret_cast<const float4*>(rp + 4);
            float2 c2 = *reinterpret_cast<const float2*>(rp + 8);
            float row[10];
            row[0] = a.x;  row[1] = a.y;  row[2] = a.z;  row[3] = a.w;
            row[4] = b4.x; row[5] = b4.y; row[6] = b4.z; row[7] = b4.w;
            row[8] = c2.x; row[9] = c2.y;
#pragma unroll
            for (int y = 0; y < 4; ++y) {
                if (y < r - 2 || y > r) continue;   // folds at compile time
                int kh = r - y;
#pragma unroll
                for (int kw = 0; kw < 3; ++kw) {
                    float w0 = w[0][kh * 3 + kw];
                    float w1 = w[1][kh * 3 + kw];
#pragma unroll
                    for (int x = 0; x < 8; ++x) {
                        acc[0][y][x] = fmaf(w0, row[x + kw], acc[0][y][x]);
                        acc[1][y][x] = fmaf(w1, row[x + kw], acc[1][y][x]);
                    }
                }
            }
        }
        if (ci < CIN - 1) {
#pragma unroll
            for (int j = 0; j < 3; ++j) { int t = tid + 256 * j; if (t < 612) in_sh[p ^ 1][lofs[j]] = sr[j]; }
            w_sh[p ^ 1][wlofs[0]] = wr[0];
            if (wv1) w_sh[p ^ 1][wlofs[1]] = wr[1];
        }
        __syncthreads();
    }

#pragma unroll
    for (int h = 0; h < 2; ++h) {
        int co = cg * 32 + co_l + 16 * h;
        float bz = bias[co];
#pragma unroll
        for (int dy = 0; dy < 2; ++dy) {
            int py = 8 * rt + 2 * ty + dy;
#pragma unroll
            for (int dx = 0; dx < 4; ++dx) {
                int px = 16 * ct + 4 * tx + dx;
                if (py < POOL && px < POOL) {
                    float v = fmaxf(fmaxf(acc[h][2 * dy][2 * dx],     acc[h][2 * dy][2 * dx + 1]),
                                    fmaxf(acc[h][2 * dy + 1][2 * dx], acc[h][2 * dy + 1][2 * dx + 1]));
                    out[(((size_t)b * COUT + co) * POOL + py) * POOL + px] = fmaxf(v + bz, 0.f);
                }
            }
        }
    }
}

// ===========================================================================
// conv3_v11: v9 structure but CI_BLK=2 -> 64 barriers instead of 128 at the
// SAME grid (512) and TLP. Targets the barrier-chain latency that pins
// conv3-v9 at VALUBusy 60% with 2 blk/CU. LDS 16.5 KB dbuf; 1152 FMA/phase.
// ===========================================================================
__global__ __launch_bounds__(256)
void conv3_v11(const float* __restrict__ in, const float* __restrict__ wt,
               const float* __restrict__ bias, float* __restrict__ out)
{
    __shared__ __align__(16) float in_sh[2][1296];   // [buf][2ci x 18*36]
    __shared__ __align__(16) float w_sh[2][768];     // [buf][2ci x 32co*12]

    int bx = blockIdx.x;
    int tile = bx & 1;
    int cg   = (bx >> 1) & 7;
    int b    = bx >> 4;
    int rt = tile;
    int tid = threadIdx.x;
    int co_l = tid & 15;
    int sp   = tid >> 4;
    int ty = sp >> 2, tx = sp & 3;
    int R0 = 16 * rt;

    // input staging offsets: chunk = 2 ci x 18x34 = 1224 floats (5 loads)
    int gofs[5], lofs[5];
#pragma unroll
    for (int j = 0; j < 5; ++j) {
        int t = tid + 256 * j; if (t > 1223) t = 1223;
        int c2 = t / 612;
        int rem = t - c2 * 612;
        int rr = rem / 34, cc = rem - rr * 34;
        int gr = R0 + rr; if (gr > 29) gr = 29;
        int gc = cc;      if (gc > 29) gc = 29;
        gofs[j] = c2 * 900 + gr * 30 + gc;
        lofs[j] = c2 * 648 + rr * 36 + cc;
    }
    // weight staging offsets: chunk = 2 ci x 32 co x 9 = 576 floats (3 loads)
    int wgofs[3], wlofs[3];
#pragma unroll
    for (int j = 0; j < 3; ++j) {
        int t = tid + 256 * j; if (t > 575) t = 575;
        int c2 = t / 288;
        int rem = t - c2 * 288;
        int c = rem / 9, k = rem - c * 9;
        wgofs[j] = (cg * 32 + c) * 1152 + c2 * 9 + k;
        wlofs[j] = c2 * 384 + c * 12 + k;
    }

    const float* gci = in + (size_t)b * 128 * 900;

    float acc[2][4][8] = {};
    float sr[5], wr[3];

    // prologue: chunk 0 (ci 0,1)
#pragma unroll
    for (int j = 0; j < 5; ++j) sr[j] = gci[gofs[j]];
#pragma unroll
    for (int j = 0; j < 3; ++j) wr[j] = wt[wgofs[j]];
#pragma unroll
    for (int j = 0; j < 5; ++j) { int t = tid + 256 * j; if (t < 1224) in_sh[0][lofs[j]] = sr[j]; }
#pragma unroll
    for (int j = 0; j < 3; ++j) { int t = tid + 256 * j; if (t < 576) w_sh[0][wlofs[j]] = wr[j]; }
    __syncthreads();

    for (int it = 0; it < 64; ++it) {
        int p = it & 1;
        // issue next chunk's loads (hidden under 1152 FMA)
        if (it < 63) {
            const float* gn = gci + (size_t)(it + 1) * 1800;
            const float* wn = wt + (size_t)(it + 1) * 18;
#pragma unroll
            for (int j = 0; j < 5; ++j) sr[j] = gn[gofs[j]];
#pragma unroll
            for (int j = 0; j < 3; ++j) wr[j] = wn[wgofs[j]];
        }
#pragma unroll
        for (int c2 = 0; c2 < 2; ++c2) {
            float w[2][9];
#pragma unroll
            for (int h = 0; h < 2; ++h)
#pragma unroll
                for (int k = 0; k < 9; ++k)
                    w[h][k] = w_sh[p][c2 * 384 + (co_l + 16 * h) * 12 + k];
            const float* rb = in_sh[p] + c2 * 648 + 8 * tx;
#pragma unroll
            for (int r = 0; r < 6; ++r) {
                const float* rp = rb + (4 * ty + r) * 36;
                float4 a = *reinterpret_cast<const float4*>(rp);
                float4 b4 = *reinterpret_cast<const float4*>(rp + 4);
                float2 c2v = *reinterpret_cast<const float2*>(rp + 8);
                float row[10];
                row[0] = a.x;  row[1] = a.y;  row[2] = a.z;  row[3] = a.w;
                row[4] = b4.x; row[5] = b4.y; row[6] = b4.z; row[7] = b4.w;
                row[8] = c2v.x; row[9] = c2v.y;
#pragma unroll
                for (int y = 0; y < 4; ++y) {
                    if (y < r - 2 || y > r) continue;   // folds at compile time
                    int kh = r - y;
#pragma unroll
                    for (int kw = 0; kw < 3; ++kw) {
                        float w0 = w[0][kh * 3 + kw];
                        float w1 = w[1][kh * 3 + kw];
#pragma unroll
                        for (int x = 0; x < 8; ++x) {
                            acc[0][y][x] = fmaf(w0, row[x + kw], acc[0][y][x]);
                            acc[1][y][x] = fmaf(w1, row[x + kw], acc[1][y][x]);
                        }
                    }
                }
            }
        }
        if (it < 63) {
#pragma unroll
            for (int j = 0; j < 5; ++j) { int t = tid + 256 * j; if (t < 1224) in_sh[p ^ 1][lofs[j]] = sr[j]; }
#pragma unroll
            for (int j = 0; j < 3; ++j) { int t = tid + 256 * j; if (t < 576) w_sh[p ^ 1][wlofs[j]] = wr[j]; }
        }
        __syncthreads();
    }

#pragma unroll
    for (int h = 0; h < 2; ++h) {
        int co = cg * 32 + co_l + 16 * h;
        float bz = bias[co];
#pragma unroll
        for (int dy = 0; dy < 2; ++dy) {
            int py = 8 * rt + 2 * ty + dy;
#pragma unroll
            for (int dx = 0; dx < 4; ++dx) {
                int px = 4 * tx + dx;
                if (py < 14 && px < 14) {
                    float v = fmaxf(fmaxf(acc[h][2 * dy][2 * dx],     acc[h][2 * dy][2 * dx + 1]),
                                    fmaxf(acc[h][2 * dy + 1][2 * dx], acc[h][2 * dy + 1][2 * dx + 1]));
                    out[(((size_t)b * 256 + co) * 14 + py) * 14 + px] = fmaxf(v + bz, 0.f);
                }
            }
        }
    }
}

// ===========================================================================
// conv4 v3: 256->512, 14x14 in, conv 12x12, pooled 6x6.
// ===========================================================================
__global__ __launch_bounds__(256)
void conv4_v3(const float* __restrict__ in, const float* __restrict__ wt,
              const float* __restrict__ bias, float* __restrict__ out)
{
    __shared__ __align__(16) float smem[4032 + 4 * 16 * 37];
    float* in_sh = smem;
    float* w_sh  = smem + 4032;
    float* red   = smem;

    int bx = blockIdx.x;
    int cg = bx & 31;
    int b  = bx >> 5;
    int tid = threadIdx.x;
    int h   = tid >> 6;
    int r6  = tid & 63;
    int cog = r6 >> 3;
    int sub = r6 & 7;
    int R = 3 * (sub >> 1), C = 6 * (sub & 1);

    float acc[2][3][6] = {};
    float sin_r[13];
    float sw_r[9];

    const size_t in_b = (size_t)b * 256 * 196;

#pragma unroll
    for (int j = 0; j < 13; ++j) {
        int g = tid + 256 * j;
        if (g < 3136) {
            int hh = g / 784, rem = g - hh * 784;
            int ci = rem / 196, r2 = rem - ci * 196;
            sin_r[j] = in[in_b + (size_t)(hh * 64 + ci) * 196 + r2];
        }
    }
#pragma unroll
    for (int j = 0; j < 9; ++j) {
        int g = tid + 256 * j;
        int hh = g / 576, rem = g - hh * 576;
        int co = rem / 36, q = rem - co * 36;
        sw_r[j] = wt[(size_t)(cg * 16 + co) * 2304 + (size_t)(hh * 64) * 9 + q];
    }

    for (int it = 0; it < 16; ++it) {
#pragma unroll
        for (int j = 0; j < 13; ++j) {
            int g = tid + 256 * j;
            if (g < 3136) {
                int hh = g / 784, rem = g - hh * 784;
                int ci = rem / 196, r2 = rem - ci * 196;
                int rr = r2 / 14, cc = r2 - rr * 14;
                in_sh[((hh * 4 + ci) * 14 + rr) * 18 + cc] = sin_r[j];
            }
        }
#pragma unroll
        for (int j = 0; j < 9; ++j) {
            int g = tid + 256 * j;
            int hh = g / 576, rem = g - hh * 576;
            int co = rem / 36, q = rem - co * 36;
            w_sh[(hh * 16 + co) * 37 + q] = sw_r[j];
        }
        __syncthreads();
        if (it < 15) {
            int k0n = (it + 1) * 4;
#pragma unroll
            for (int j = 0; j < 13; ++j) {
                int g = tid + 256 * j;
                if (g < 3136) {
                    int hh = g / 784, rem = g - hh * 784;
                    int ci = rem / 196, r2 = rem - ci * 196;
                    sin_r[j] = in[in_b + (size_t)(hh * 64 + k0n + ci) * 196 + r2];
                }
            }
#pragma unroll
            for (int j = 0; j < 9; ++j) {
                int g = tid + 256 * j;
                int hh = g / 576, rem = g - hh * 576;
                int co = rem / 36, q = rem - co * 36;
                sw_r[j] = wt[(size_t)(cg * 16 + co) * 2304 + (size_t)(hh * 64 + k0n) * 9 + q];
            }
        }
#pragma unroll
        for (int ci = 0; ci < 4; ++ci) {
            float w[2][9];
#pragma unroll
            for (int c = 0; c < 2; ++c)
#pragma unroll
                for (int k = 0; k < 9; ++k)
                    w[c][k] = w_sh[(h * 16 + 2 * cog + c) * 37 + ci * 9 + k];
            const float* rowbase = in_sh + ((h * 4 + ci) * 14) * 18;
#pragma unroll
            for (int r = 0; r < 5; ++r) {
                float row[8];
                const float2* pr = reinterpret_cast<const float2*>(rowbase + (size_t)(R + r) * 18 + C);
                float2 a0 = pr[0], a1 = pr[1], a2 = pr[2], a3 = pr[3];
                row[0] = a0.x; row[1] = a0.y; row[2] = a1.x; row[3] = a1.y;
                row[4] = a2.x; row[5] = a2.y; row[6] = a3.x; row[7] = a3.y;
#pragma unroll
                for (int y = 0; y < 3; ++y) {
                    if (y < r - 2 || y > r) continue;
                    int kh = r - y;
#pragma unroll
                    for (int c = 0; c < 2; ++c)
#pragma unroll
                        for (int kw = 0; kw < 3; ++kw) {
                            float wv = w[c][kh * 3 + kw];
#pragma unroll
                            for (int x = 0; x < 6; ++x)
                                acc[c][y][x] = fmaf(wv, row[x + kw], acc[c][y][x]);
                        }
                }
            }
        }
        __syncthreads();
    }
#pragma unroll
    for (int hh = 0; hh < 4; ++hh) {
        if (h == hh) {
#pragma unroll
            for (int c = 0; c < 2; ++c)
#pragma unroll
                for (int y = 0; y < 3; ++y)
#pragma unroll
                    for (int x = 0; x < 6; ++x) {
                        float* dst = &red[((2 * cog + c) * 12 + R + y) * 13 + C + x];
                        if (hh == 0) *dst = acc[c][y][x];
                        else         *dst += acc[c][y][x];
                    }
        }
        __syncthreads();
    }
    for (int t = tid; t < 576; t += 256) {
        int co = t / 36, rem = t - co * 36;
        int pr = rem / 6, pc = rem - pr * 6;
        const float* rp = &red[(co * 12 + 2 * pr) * 13 + 2 * pc];
        float v = fmaxf(fmaxf(rp[0], rp[1]), fmaxf(rp[13], rp[14]));
        v += bias[cg * 16 + co];
        out[(((size_t)b * 512 + cg * 16 + co) * 6 + pr) * 6 + pc] = fmaxf(v, 0.f);
    }
}

// ===========================================================================
// fc_big: Y[b, o0+o] = act(X[b,:].W[o0+o,:] + bias), 8 outputs per block.
// ===========================================================================
__global__ __launch_bounds__(1024)
void fc_big(const float* __restrict__ X, const float* __restrict__ W,
            const float* __restrict__ bias, float* __restrict__ Y,
            int K, int N, int act)
{
    __shared__ float red[32][32][8];
    int o0 = blockIdx.x * 8;
    int s = threadIdx.x & 31;
    int b = threadIdx.x >> 5;
    int K4 = K >> 2;
    const float4* X4 = reinterpret_cast<const float4*>(X) + (size_t)b * K4;
    const float4* W4 = reinterpret_cast<const float4*>(W);

    float acc[8] = {};
    for (int k4 = s; k4 < K4; k4 += 32) {
        float4 xv = X4[k4];
#pragma unroll
        for (int o = 0; o < 8; ++o) {
            float4 wv = W4[(size_t)(o0 + o) * K4 + k4];
            acc[o] = fmaf(xv.x, wv.x,
                     fmaf(xv.y, wv.y,
                     fmaf(xv.z, wv.z,
                     fmaf(xv.w, wv.w, acc[o]))));
        }
    }
#pragma unroll
    for (int o = 0; o < 8; ++o) red[b][s][o] = acc[o];
    __syncthreads();
    if (threadIdx.x < 256) {
        int bb = threadIdx.x >> 3, oo = threadIdx.x & 7;
        float v = bias[o0 + oo];
#pragma unroll 8
        for (int ss = 0; ss < 32; ++ss) v += red[bb][ss][oo];
        if (act) v = tanhf(v);
        Y[(size_t)bb * N + o0 + oo] = v;
    }
}

// ---------------------------------------------------------------------------
// fc_two: small heads (N = 2, 30, 10).
// ---------------------------------------------------------------------------
__global__ __launch_bounds__(256)
void fc_two(const float* __restrict__ X, const float* __restrict__ W,
            const float* __restrict__ bias, float* __restrict__ Y,
            int K, int N, int act)
{
    int o0 = blockIdx.x * 2;
    int tid = threadIdx.x;
    const float* w0 = W + (size_t)o0 * K;
    const float* w1 = w0 + K;
    float a0[32], a1[32];
#pragma unroll
    for (int b = 0; b < 32; ++b) { a0[b] = 0.f; a1[b] = 0.f; }

    for (int k = tid; k < K; k += 256) {
        float wv0 = w0[k], wv1 = w1[k];
#pragma unroll
        for (int b = 0; b < 32; ++b) {
            float xv = X[(size_t)b * K + k];
            a0[b] = fmaf(wv0, xv, a0[b]);
            a1[b] = fmaf(wv1, xv, a1[b]);
        }
    }
    __shared__ float part[2][4][32];
    int lane = tid & 63, wv = tid >> 6;
#pragma unroll
    for (int b = 0; b < 32; ++b) {
        float s0 = a0[b], s1 = a1[b];
#pragma unroll
        for (int off = 32; off >= 1; off >>= 1) {
            s0 += __shfl_down(s0, off);
            s1 += __shfl_down(s1, off);
        }
        if (lane == 0) { part[0][wv][b] = s0; part[1][wv][b] = s1; }
    }
    __syncthreads();
    if (tid < 64) {
        int j = tid >> 5, b = tid & 31;
        float s = part[j][0][b] + part[j][1][b] + part[j][2][b] + part[j][3][b] + bias[o0 + j];
        if (act) s = tanhf(s);
        Y[(size_t)b * N + o0 + j] = s;
    }
}

// ---------------------------------------------------------------------------
// softmax over 10 logits -> ratio (output), then seg_limit rebalance
// ---------------------------------------------------------------------------
__global__ __launch_bounds__(64)
void post_kernel(const float* __restrict__ logits, float* __restrict__ ratio_out,
                 float* __restrict__ sl_out)
{
    int b = threadIdx.x;
    if (b >= 32) return;
    float lg[10];
#pragma unroll
    for (int j = 0; j < 10; ++j) lg[j] = logits[b * 10 + j];
    float mx = lg[0];
#pragma unroll
    for (int j = 1; j < 10; ++j) mx = fmaxf(mx, lg[j]);
    float e[10]; float ssum = 0.f;
#pragma unroll
    for (int j = 0; j < 10; ++j) { e[j] = expf(lg[j] - mx); ssum += e[j]; }
    float sl[10];
#pragma unroll
    for (int j = 0; j < 10; ++j) {
        float r = e[j] / ssum;
        ratio_out[b * 10 + j] = r;
        sl[j] = ceilf(r * 200.f);
    }
#pragma unroll
    for (int it = 0; it < 10; ++it) {
        float s = 0.f, mx2 = sl[0];
#pragma unroll
        for (int j = 0; j < 10; ++j) { s += sl[j]; mx2 = fmaxf(mx2, sl[j]); }
        float over = (s != 200.f) ? 1.f : 0.f;
        float reduced = 1.f;
#pragma unroll
        for (int j = 0; j < 10; ++j) {
            float mult = (sl[j] == mx2) ? 1.f : 0.f;
            sl[j] -= mult * reduced * over;
            reduced = fmaxf(reduced - mult, 0.f);
        }
    }
#pragma unroll
    for (int j = 0; j < 10; ++j) sl_out[b * 10 + j] = sl[j];
}

// ---------------------------------------------------------------------------
// trajectory assembly: grid 32 (batch), 256 threads (200 active points)
// ---------------------------------------------------------------------------
__global__ __launch_bounds__(256)
void traj_kernel(const float* __restrict__ base, const float* __restrict__ ipos,
                 const float* __restrict__ sm, float* __restrict__ out_traj,
                 float* __restrict__ out_starts)
{
    int b = blockIdx.x;
    int j = threadIdx.x;
    float bx0 = base[0], by0 = base[1];
    float bxL = base[398], byL = base[399];
    float bx = 0.f, by = 0.f;
    if (j < 200) { bx = base[2 * j]; by = base[2 * j + 1]; }
    float curx = ipos[b * 2 + 0], cury = ipos[b * 2 + 1];
    if (j == 0) { out_starts[b * 22 + 0] = curx; out_starts[b * 22 + 1] = cury; }
#pragma unroll
    for (int i = 0; i < 10; ++i) {
        float sx  = sm[b * 30 + i * 3 + 0];
        float sy  = sm[b * 30 + i * 3 + 1];
        float rot = tanhf(sm[b * 30 + i * 3 + 2]) * 3.14f;
        float c = cosf(rot), s = sinf(rot);
        float cx = bx0 * sx, cy = by0 * sy;
        if (j < 200) {
            float px = bx * sx, py = by * sy;
            float rx = c * (px - cx) - s * (py - cy) + cx;
            float ry = s * (px - cx) + c * (py - cy) + cy;
            size_t o = ((size_t)b * 2000 + i * 200 + j) * 2;
            out_traj[o + 0] = curx + rx;
            out_traj[o + 1] = cury + ry;
        }
        float pxL = bxL * sx, pyL = byL * sy;
        float exL = c * (pxL - cx) - s * (pyL - cy) + cx;
        float eyL = s * (pxL - cx) + c * (pyL - cy) + cy;
        curx += exL; cury += eyL;
        if (j == 0) {
            out_starts[b * 22 + (i + 1) * 2 + 0] = curx;
            out_starts[b * 22 + (i + 1) * 2 + 1] = cury;
        }
    }
}

// ---------------------------------------------------------------------------
// sampler: event-jump exact reimplementation of the reference scan.
// ---------------------------------------------------------------------------
__global__ __launch_bounds__(64)
void sample_kernel(const float* __restrict__ sl_in, const float* __restrict__ traj,
                   float* __restrict__ samp_out)
{
    __shared__ unsigned int maskb[32][63];
    __shared__ float ssl[32][10];
    int tid = threadIdx.x;
    for (int t = tid; t < 32 * 63; t += 64) ((unsigned int*)maskb)[t] = 0u;
    for (int t = tid; t < 32 * 10; t += 64) ((float*)ssl)[t] = sl_in[t];
    __syncthreads();
    if (tid >= 32) return;
    int b = tid;
    const float* tb = traj + (size_t)b * 4000;
    float* sp = samp_out + (size_t)b * 400;
    int out_n = 0;
    float last = 0.f, ntot = 0.f;
    float lim0 = ssl[b][0];
    float di = floorf(199.f / lim0);
    float ct0 = 0.f;
    if ((ntot < 200.f) && (ct0 < lim0) && (0.f - last == di)) {
        ntot += 1.f; ct0 += 1.f;
        maskb[b][0] |= 1u;
        sp[out_n * 2] = tb[0]; sp[out_n * 2 + 1] = tb[1]; ++out_n;
    }
    {
        float ndi = floorf((199.f - last) / (lim0 - ct0));
        if (di < ndi) di = ndi;
        if ((ntot < 200.f) && (ct0 < lim0) && (1.f - last == di)) {
            last = 1.f; ntot += 1.f; ct0 += 1.f;
            maskb[b][0] |= 2u;
            sp[out_n * 2] = tb[2]; sp[out_n * 2 + 1] = tb[3]; ++out_n;
        }
    }
    for (int seg = 0; seg < 10; ++seg) {
        float lim = ssl[b][seg];
        float ct = (seg == 0) ? ct0 : 0.f;
        float segbase = 200.f * seg;
        float segend = segbase + 199.f;
        float pos = (seg == 0) ? 2.f : segbase;
        float ndi = floorf((199.f - (last - segbase)) / (lim - ct));
        while ((ntot < 200.f) && (ct < lim)) {
            float fi = last + ndi;
            if (!(fi >= pos && fi <= segend)) break;
            int i = (int)fi;
            last = fi; ntot += 1.f; ct += 1.f;
            maskb[b][i >> 5] |= (1u << (i & 31));
            sp[out_n * 2] = tb[2 * i]; sp[out_n * 2 + 1] = tb[2 * i + 1]; ++out_n;
            pos = fi + 1.f;
            ndi = floorf((199.f - (last - segbase)) / (lim - ct));
        }
    }
    for (int i = 0; i < 2000 && out_n < 200; ++i) {
        if (!((maskb[b][i >> 5] >> (i & 31)) & 1u)) {
            sp[out_n * 2] = tb[2 * i]; sp[out_n * 2 + 1] = tb[2 * i + 1]; ++out_n;
        }
    }
}

// ---------------------------------------------------------------------------
extern "C" void kernel_launch(void* const* d_in, const int* in_sizes, int n_in,
                              void* d_out, int out_size, void* d_ws, size_t ws_size,
                              hipStream_t stream)
{
    const float* x    = (const float*)d_in[0];
    const float* w1   = (const float*)d_in[1];
    const float* b1   = (const float*)d_in[2];
    const float* w2   = (const float*)d_in[3];
    const float* b2   = (const float*)d_in[4];
    const float* w3   = (const float*)d_in[5];
    const float* b3   = (const float*)d_in[6];
    const float* w4   = (const float*)d_in[7];
    const float* b4   = (const float*)d_in[8];
    const float* fcw1 = (const float*)d_in[9];
    const float* fcb1 = (const float*)d_in[10];
    const float* fcw2 = (const float*)d_in[11];
    const float* fcb2 = (const float*)d_in[12];
    const float* wi   = (const float*)d_in[13];
    const float* bi   = (const float*)d_in[14];
    const float* wsw  = (const float*)d_in[15];
    const float* bs   = (const float*)d_in[16];
    const float* wr   = (const float*)d_in[17];
    const float* br   = (const float*)d_in[18];
    const float* base = (const float*)d_in[19];

    float* out = (float*)d_out;
    float* ws  = (float*)d_ws;

    float* p1   = ws + 0;        // 32x64x63x63   (8,128,512)
    float* p2   = ws + 8128512;  // 32x128x30x30  (3,686,400)
    float* p3   = ws + 0;        // 32x256x14x14  (reuses p1)
    float* feat = ws + 8128512;  // 32x512x6x6    (reuses p2)
    float* z1   = ws + 0;        // 32x2048       (reuses p3)
    float* z2   = ws + 65536;    // 32x2048
    float* ipos = ws + 131072;   // 32x2
    float* smod = ws + 131136;   // 32x30
    float* rlog = ws + 132096;   // 32x10
    float* slim = ws + 132416;   // 32x10

    float* out_samp   = out;            // 32*200*2 = 12800
    float* out_starts = out + 12800;    // 32*11*2  = 704
    float* out_ratio  = out + 13504;    // 32*10    = 320
    float* out_traj   = out + 13824;    // 32*2000*2 = 128000

    conv1_lds<<<4096, 256, 0, stream>>>(x, w1, b1, p1);
    conv_v9<64, 63, 30, 128, 4, 2><<<1024, 256, 0, stream>>>(p1, w2, b2, p2);
    conv3_v11<<<512, 256, 0, stream>>>(p2, w3, b3, p3);
    conv4_v3<<<1024, 256, 0, stream>>>(p3, w4, b4, feat);

    fc_big<<<256, 1024, 0, stream>>>(feat, fcw1, fcb1, z1, 18432, 2048, 1);
    fc_big<<<256, 1024, 0, stream>>>(z1, fcw2, fcb2, z2, 2048, 2048, 0);

    fc_two<<<1, 256, 0, stream>>>(z2, wi, bi, ipos, 2048, 2, 0);
    fc_two<<<15, 256, 0, stream>>>(z2, wsw, bs, smod, 2048, 30, 0);
    fc_two<<<5, 256, 0, stream>>>(z2, wr, br, rlog, 2048, 10, 0);

    post_kernel<<<1, 64, 0, stream>>>(rlog, out_ratio, slim);
    traj_kernel<<<32, 256, 0, stream>>>(base, ipos, smod, out_traj, out_starts);
    sample_kernel<<<1, 64, 0, stream>>>(slim, out_traj, out_samp);
}

// Round 17
// 973.442 us; speedup vs baseline: 1.0722x; 1.0722x over previous
//
#include <hip/hip_runtime.h>

// ===========================================================================
// conv1: 3->64, 128x128 in, pooled 63x63.
// ===========================================================================
__global__ __launch_bounds__(256)
void conv1_lds(const float* __restrict__ in, const float* __restrict__ wt,
               const float* __restrict__ bias, float* __restrict__ out)
{
    __shared__ float sh[3][34][34];
    int bx = blockIdx.x;
    int tile = bx & 15;
    int cg   = (bx >> 4) & 7;
    int b    = bx >> 7;
    int tr = tile >> 2, tc = tile & 3;
    int tid = threadIdx.x;
    int ty = tid >> 4, tx = tid & 15;
    int R0 = 32 * tr, C0 = 32 * tc;

    for (int t = tid; t < 3 * 34 * 34; t += 256) {
        int ci = t / 1156;
        int rem = t - ci * 1156;
        int rr = rem / 34, cc = rem - rr * 34;
        int gr = R0 + rr; if (gr > 127) gr = 127;
        int gc = C0 + cc; if (gc > 127) gc = 127;
        sh[ci][rr][cc] = in[(((size_t)b * 3 + ci) * 128 + gr) * 128 + gc];
    }
    __syncthreads();

    float acc[8][2][2] = {};
    int co0 = cg * 8;
#pragma unroll
    for (int ci = 0; ci < 3; ++ci) {
        float p[4][4];
#pragma unroll
        for (int r = 0; r < 4; ++r) {
            const float2* pr = reinterpret_cast<const float2*>(&sh[ci][2 * ty + r][2 * tx]);
            float2 a = pr[0], c2 = pr[1];
            p[r][0] = a.x; p[r][1] = a.y; p[r][2] = c2.x; p[r][3] = c2.y;
        }
#pragma unroll
        for (int j = 0; j < 8; ++j) {
            const float* wj = wt + ((size_t)(co0 + j) * 3 + ci) * 9;
#pragma unroll
            for (int kh = 0; kh < 3; ++kh)
#pragma unroll
                for (int kw = 0; kw < 3; ++kw) {
                    float wv = wj[kh * 3 + kw];
#pragma unroll
                    for (int dy = 0; dy < 2; ++dy)
#pragma unroll
                        for (int dx = 0; dx < 2; ++dx)
                            acc[j][dy][dx] = fmaf(wv, p[dy + kh][dx + kw], acc[j][dy][dx]);
                }
        }
    }
    int py = 16 * tr + ty, px = 16 * tc + tx;
    if (py < 63 && px < 63) {
#pragma unroll
        for (int j = 0; j < 8; ++j) {
            float v = fmaxf(fmaxf(acc[j][0][0], acc[j][0][1]),
                            fmaxf(acc[j][1][0], acc[j][1][1])) + bias[co0 + j];
            out[(((size_t)b * 64 + co0 + j) * 63 + py) * 63 + px] = fmaxf(v, 0.f);
        }
    }
}

// ===========================================================================
// conv_v9 (conv2 AND conv3): CO=2 per thread -> LDS bytes/FMA 0.54.
// Session-best structure (rounds 10-16 A/B series):
//  - LDS return BW is the conv wall (v4 vs v5 vs v7 all ~279 at 0.96 B/FMA;
//    CO=2 at 0.54 B/FMA wins when spill-lean).
//  - VGPR must stay <=128 (4 waves): v5 (104+spill) and v11 (136, occ 11%)
//    both lose; keep ci-chunk=1 staging (sr[3]/wr[2]).
//  - conv3@512 blocks (2 blk/CU) is its plateau: finer tiles (286), CI_BLK=2
//    (342), ci-split+atomics (577, HBM RMW trap) all regress vs 270.
// ===========================================================================
template<int CIN, int DIM, int POOL, int COUT, int TILES_R, int TILES_C>
__global__ __launch_bounds__(256)
void conv_v9(const float* __restrict__ in, const float* __restrict__ wt,
             const float* __restrict__ bias, float* __restrict__ out)
{
    __shared__ __align__(16) float in_sh[2][648];   // [buf][18*36]
    __shared__ __align__(16) float w_sh[2][384];    // [buf][32 co * 12]

    constexpr int NT  = TILES_R * TILES_C;
    constexpr int NCG = COUT / 32;
    int bx = blockIdx.x;
    int tile = bx % NT;
    int cg   = (bx / NT) % NCG;
    int b    = bx / (NT * NCG);
    int rt = tile / TILES_C, ct = tile % TILES_C;
    int tid = threadIdx.x;
    int co_l = tid & 15;
    int sp   = tid >> 4;
    int ty = sp >> 2, tx = sp & 3;
    int R0 = 16 * rt, C0 = 32 * ct;

    int gofs[3], lofs[3];
#pragma unroll
    for (int j = 0; j < 3; ++j) {
        int t = tid + 256 * j; if (t > 611) t = 611;
        int rr = t / 34, cc = t - rr * 34;
        int gr = R0 + rr; if (gr > DIM - 1) gr = DIM - 1;
        int gc = C0 + cc; if (gc > DIM - 1) gc = DIM - 1;
        gofs[j] = gr * DIM + gc;
        lofs[j] = rr * 36 + cc;
    }
    int wgofs[2], wlofs[2];
#pragma unroll
    for (int j = 0; j < 2; ++j) {
        int t = tid + 256 * j; if (t > 287) t = 287;
        int c = t / 9, k = t - c * 9;
        wgofs[j] = (cg * 32 + c) * CIN * 9 + k;
        wlofs[j] = c * 12 + k;
    }
    bool wv1 = (tid < 32);

    const float* gci = in + (size_t)b * CIN * DIM * DIM;
    const float* wci = wt;

    float acc[2][4][8] = {};
    float sr[3], wr[2];

#pragma unroll
    for (int j = 0; j < 3; ++j) sr[j] = gci[gofs[j]];
    wr[0] = wci[wgofs[0]];
    wr[1] = wci[wgofs[1]];
#pragma unroll
    for (int j = 0; j < 3; ++j) { int t = tid + 256 * j; if (t < 612) in_sh[0][lofs[j]] = sr[j]; }
    w_sh[0][wlofs[0]] = wr[0];
    if (wv1) w_sh[0][wlofs[1]] = wr[1];
    __syncthreads();

    for (int ci = 0; ci < CIN; ++ci) {
        int p = ci & 1;
        if (ci < CIN - 1) {
            const float* gn = gci + (size_t)(ci + 1) * DIM * DIM;
            const float* wn = wci + (size_t)(ci + 1) * 9;
#pragma unroll
            for (int j = 0; j < 3; ++j) sr[j] = gn[gofs[j]];
            wr[0] = wn[wgofs[0]];
            wr[1] = wn[wgofs[1]];
        }
        float w[2][9];
#pragma unroll
        for (int h = 0; h < 2; ++h)
#pragma unroll
            for (int k = 0; k < 9; ++k)
                w[h][k] = w_sh[p][(co_l + 16 * h) * 12 + k];
        const float* rb = in_sh[p] + 8 * tx;
#pragma unroll
        for (int r = 0; r < 6; ++r) {
            const float* rp = rb + (4 * ty + r) * 36;
            float4 a = *reinterpret_cast<const float4*>(rp);
            float4 b4 = *reinterpret_cast<const float4*>(rp + 4);
            float2 c2 = *reinterpret_cast<const float2*>(rp + 8);
            float row[10];
            row[0] = a.x;  row[1] = a.y;  row[2] = a.z;  row[3] = a.w;
            row[4] = b4.x; row[5] = b4.y; row[6] = b4.z; row[7] = b4.w;
            row[8] = c2.x; row[9] = c2.y;
#pragma unroll
            for (int y = 0; y < 4; ++y) {
                if (y < r - 2 || y > r) continue;   // folds at compile time
                int kh = r - y;
#pragma unroll
                for (int kw = 0; kw < 3; ++kw) {
                    float w0 = w[0][kh * 3 + kw];
                    float w1 = w[1][kh * 3 + kw];
#pragma unroll
                    for (int x = 0; x < 8; ++x) {
                        acc[0][y][x] = fmaf(w0, row[x + kw], acc[0][y][x]);
                        acc[1][y][x] = fmaf(w1, row[x + kw], acc[1][y][x]);
                    }
                }
            }
        }
        if (ci < CIN - 1) {
#pragma unroll
            for (int j = 0; j < 3; ++j) { int t = tid + 256 * j; if (t < 612) in_sh[p ^ 1][lofs[j]] = sr[j]; }
            w_sh[p ^ 1][wlofs[0]] = wr[0];
            if (wv1) w_sh[p ^ 1][wlofs[1]] = wr[1];
        }
        __syncthreads();
    }

#pragma unroll
    for (int h = 0; h < 2; ++h) {
        int co = cg * 32 + co_l + 16 * h;
        float bz = bias[co];
#pragma unroll
        for (int dy = 0; dy < 2; ++dy) {
            int py = 8 * rt + 2 * ty + dy;
#pragma unroll
            for (int dx = 0; dx < 4; ++dx) {
                int px = 16 * ct + 4 * tx + dx;
                if (py < POOL && px < POOL) {
                    float v = fmaxf(fmaxf(acc[h][2 * dy][2 * dx],     acc[h][2 * dy][2 * dx + 1]),
                                    fmaxf(acc[h][2 * dy + 1][2 * dx], acc[h][2 * dy + 1][2 * dx + 1]));
                    out[(((size_t)b * COUT + co) * POOL + py) * POOL + px] = fmaxf(v + bz, 0.f);
                }
            }
        }
    }
}

// ===========================================================================
// conv4 v3: 256->512, 14x14 in, conv 12x12, pooled 6x6.
// ===========================================================================
__global__ __launch_bounds__(256)
void conv4_v3(const float* __restrict__ in, const float* __restrict__ wt,
              const float* __restrict__ bias, float* __restrict__ out)
{
    __shared__ __align__(16) float smem[4032 + 4 * 16 * 37];
    float* in_sh = smem;
    float* w_sh  = smem + 4032;
    float* red   = smem;

    int bx = blockIdx.x;
    int cg = bx & 31;
    int b  = bx >> 5;
    int tid = threadIdx.x;
    int h   = tid >> 6;
    int r6  = tid & 63;
    int cog = r6 >> 3;
    int sub = r6 & 7;
    int R = 3 * (sub >> 1), C = 6 * (sub & 1);

    float acc[2][3][6] = {};
    float sin_r[13];
    float sw_r[9];

    const size_t in_b = (size_t)b * 256 * 196;

#pragma unroll
    for (int j = 0; j < 13; ++j) {
        int g = tid + 256 * j;
        if (g < 3136) {
            int hh = g / 784, rem = g - hh * 784;
            int ci = rem / 196, r2 = rem - ci * 196;
            sin_r[j] = in[in_b + (size_t)(hh * 64 + ci) * 196 + r2];
        }
    }
#pragma unroll
    for (int j = 0; j < 9; ++j) {
        int g = tid + 256 * j;
        int hh = g / 576, rem = g - hh * 576;
        int co = rem / 36, q = rem - co * 36;
        sw_r[j] = wt[(size_t)(cg * 16 + co) * 2304 + (size_t)(hh * 64) * 9 + q];
    }

    for (int it = 0; it < 16; ++it) {
#pragma unroll
        for (int j = 0; j < 13; ++j) {
            int g = tid + 256 * j;
            if (g < 3136) {
                int hh = g / 784, rem = g - hh * 784;
                int ci = rem / 196, r2 = rem - ci * 196;
                int rr = r2 / 14, cc = r2 - rr * 14;
                in_sh[((hh * 4 + ci) * 14 + rr) * 18 + cc] = sin_r[j];
            }
        }
#pragma unroll
        for (int j = 0; j < 9; ++j) {
            int g = tid + 256 * j;
            int hh = g / 576, rem = g - hh * 576;
            int co = rem / 36, q = rem - co * 36;
            w_sh[(hh * 16 + co) * 37 + q] = sw_r[j];
        }
        __syncthreads();
        if (it < 15) {
            int k0n = (it + 1) * 4;
#pragma unroll
            for (int j = 0; j < 13; ++j) {
                int g = tid + 256 * j;
                if (g < 3136) {
                    int hh = g / 784, rem = g - hh * 784;
                    int ci = rem / 196, r2 = rem - ci * 196;
                    sin_r[j] = in[in_b + (size_t)(hh * 64 + k0n + ci) * 196 + r2];
                }
            }
#pragma unroll
            for (int j = 0; j < 9; ++j) {
                int g = tid + 256 * j;
                int hh = g / 576, rem = g - hh * 576;
                int co = rem / 36, q = rem - co * 36;
                sw_r[j] = wt[(size_t)(cg * 16 + co) * 2304 + (size_t)(hh * 64 + k0n) * 9 + q];
            }
        }
#pragma unroll
        for (int ci = 0; ci < 4; ++ci) {
            float w[2][9];
#pragma unroll
            for (int c = 0; c < 2; ++c)
#pragma unroll
                for (int k = 0; k < 9; ++k)
                    w[c][k] = w_sh[(h * 16 + 2 * cog + c) * 37 + ci * 9 + k];
            const float* rowbase = in_sh + ((h * 4 + ci) * 14) * 18;
#pragma unroll
            for (int r = 0; r < 5; ++r) {
                float row[8];
                const float2* pr = reinterpret_cast<const float2*>(rowbase + (size_t)(R + r) * 18 + C);
                float2 a0 = pr[0], a1 = pr[1], a2 = pr[2], a3 = pr[3];
                row[0] = a0.x; row[1] = a0.y; row[2] = a1.x; row[3] = a1.y;
                row[4] = a2.x; row[5] = a2.y; row[6] = a3.x; row[7] = a3.y;
#pragma unroll
                for (int y = 0; y < 3; ++y) {
                    if (y < r - 2 || y > r) continue;
                    int kh = r - y;
#pragma unroll
                    for (int c = 0; c < 2; ++c)
#pragma unroll
                        for (int kw = 0; kw < 3; ++kw) {
                            float wv = w[c][kh * 3 + kw];
#pragma unroll
                            for (int x = 0; x < 6; ++x)
                                acc[c][y][x] = fmaf(wv, row[x + kw], acc[c][y][x]);
                        }
                }
            }
        }
        __syncthreads();
    }
#pragma unroll
    for (int hh = 0; hh < 4; ++hh) {
        if (h == hh) {
#pragma unroll
            for (int c = 0; c < 2; ++c)
#pragma unroll
                for (int y = 0; y < 3; ++y)
#pragma unroll
                    for (int x = 0; x < 6; ++x) {
                        float* dst = &red[((2 * cog + c) * 12 + R + y) * 13 + C + x];
                        if (hh == 0) *dst = acc[c][y][x];
                        else         *dst += acc[c][y][x];
                    }
        }
        __syncthreads();
    }
    for (int t = tid; t < 576; t += 256) {
        int co = t / 36, rem = t - co * 36;
        int pr = rem / 6, pc = rem - pr * 6;
        const float* rp = &red[(co * 12 + 2 * pr) * 13 + 2 * pc];
        float v = fmaxf(fmaxf(rp[0], rp[1]), fmaxf(rp[13], rp[14]));
        v += bias[cg * 16 + co];
        out[(((size_t)b * 512 + cg * 16 + co) * 6 + pr) * 6 + pc] = fmaxf(v, 0.f);
    }
}

// ===========================================================================
// fc_big: Y[b, o0+o] = act(X[b,:].W[o0+o,:] + bias), 8 outputs per block.
// ===========================================================================
__global__ __launch_bounds__(1024)
void fc_big(const float* __restrict__ X, const float* __restrict__ W,
            const float* __restrict__ bias, float* __restrict__ Y,
            int K, int N, int act)
{
    __shared__ float red[32][32][8];
    int o0 = blockIdx.x * 8;
    int s = threadIdx.x & 31;
    int b = threadIdx.x >> 5;
    int K4 = K >> 2;
    const float4* X4 = reinterpret_cast<const float4*>(X) + (size_t)b * K4;
    const float4* W4 = reinterpret_cast<const float4*>(W);

    float acc[8] = {};
    for (int k4 = s; k4 < K4; k4 += 32) {
        float4 xv = X4[k4];
#pragma unroll
        for (int o = 0; o < 8; ++o) {
            float4 wv = W4[(size_t)(o0 + o) * K4 + k4];
            acc[o] = fmaf(xv.x, wv.x,
                     fmaf(xv.y, wv.y,
                     fmaf(xv.z, wv.z,
                     fmaf(xv.w, wv.w, acc[o]))));
        }
    }
#pragma unroll
    for (int o = 0; o < 8; ++o) red[b][s][o] = acc[o];
    __syncthreads();
    if (threadIdx.x < 256) {
        int bb = threadIdx.x >> 3, oo = threadIdx.x & 7;
        float v = bias[o0 + oo];
#pragma unroll 8
        for (int ss = 0; ss < 32; ++ss) v += red[bb][ss][oo];
        if (act) v = tanhf(v);
        Y[(size_t)bb * N + o0 + oo] = v;
    }
}

// ---------------------------------------------------------------------------
// fc_two: small heads (N = 2, 30, 10).
// ---------------------------------------------------------------------------
__global__ __launch_bounds__(256)
void fc_two(const float* __restrict__ X, const float* __restrict__ W,
            const float* __restrict__ bias, float* __restrict__ Y,
            int K, int N, int act)
{
    int o0 = blockIdx.x * 2;
    int tid = threadIdx.x;
    const float* w0 = W + (size_t)o0 * K;
    const float* w1 = w0 + K;
    float a0[32], a1[32];
#pragma unroll
    for (int b = 0; b < 32; ++b) { a0[b] = 0.f; a1[b] = 0.f; }

    for (int k = tid; k < K; k += 256) {
        float wv0 = w0[k], wv1 = w1[k];
#pragma unroll
        for (int b = 0; b < 32; ++b) {
            float xv = X[(size_t)b * K + k];
            a0[b] = fmaf(wv0, xv, a0[b]);
            a1[b] = fmaf(wv1, xv, a1[b]);
        }
    }
    __shared__ float part[2][4][32];
    int lane = tid & 63, wv = tid >> 6;
#pragma unroll
    for (int b = 0; b < 32; ++b) {
        float s0 = a0[b], s1 = a1[b];
#pragma unroll
        for (int off = 32; off >= 1; off >>= 1) {
            s0 += __shfl_down(s0, off);
            s1 += __shfl_down(s1, off);
        }
        if (lane == 0) { part[0][wv][b] = s0; part[1][wv][b] = s1; }
    }
    __syncthreads();
    if (tid < 64) {
        int j = tid >> 5, b = tid & 31;
        float s = part[j][0][b] + part[j][1][b] + part[j][2][b] + part[j][3][b] + bias[o0 + j];
        if (act) s = tanhf(s);
        Y[(size_t)b * N + o0 + j] = s;
    }
}

// ---------------------------------------------------------------------------
// softmax over 10 logits -> ratio (output), then seg_limit rebalance
// ---------------------------------------------------------------------------
__global__ __launch_bounds__(64)
void post_kernel(const float* __restrict__ logits, float* __restrict__ ratio_out,
                 float* __restrict__ sl_out)
{
    int b = threadIdx.x;
    if (b >= 32) return;
    float lg[10];
#pragma unroll
    for (int j = 0; j < 10; ++j) lg[j] = logits[b * 10 + j];
    float mx = lg[0];
#pragma unroll
    for (int j = 1; j < 10; ++j) mx = fmaxf(mx, lg[j]);
    float e[10]; float ssum = 0.f;
#pragma unroll
    for (int j = 0; j < 10; ++j) { e[j] = expf(lg[j] - mx); ssum += e[j]; }
    float sl[10];
#pragma unroll
    for (int j = 0; j < 10; ++j) {
        float r = e[j] / ssum;
        ratio_out[b * 10 + j] = r;
        sl[j] = ceilf(r * 200.f);
    }
#pragma unroll
    for (int it = 0; it < 10; ++it) {
        float s = 0.f, mx2 = sl[0];
#pragma unroll
        for (int j = 0; j < 10; ++j) { s += sl[j]; mx2 = fmaxf(mx2, sl[j]); }
        float over = (s != 200.f) ? 1.f : 0.f;
        float reduced = 1.f;
#pragma unroll
        for (int j = 0; j < 10; ++j) {
            float mult = (sl[j] == mx2) ? 1.f : 0.f;
            sl[j] -= mult * reduced * over;
            reduced = fmaxf(reduced - mult, 0.f);
        }
    }
#pragma unroll
    for (int j = 0; j < 10; ++j) sl_out[b * 10 + j] = sl[j];
}

// ---------------------------------------------------------------------------
// trajectory assembly: grid 32 (batch), 256 threads (200 active points)
// ---------------------------------------------------------------------------
__global__ __launch_bounds__(256)
void traj_kernel(const float* __restrict__ base, const float* __restrict__ ipos,
                 const float* __restrict__ sm, float* __restrict__ out_traj,
                 float* __restrict__ out_starts)
{
    int b = blockIdx.x;
    int j = threadIdx.x;
    float bx0 = base[0], by0 = base[1];
    float bxL = base[398], byL = base[399];
    float bx = 0.f, by = 0.f;
    if (j < 200) { bx = base[2 * j]; by = base[2 * j + 1]; }
    float curx = ipos[b * 2 + 0], cury = ipos[b * 2 + 1];
    if (j == 0) { out_starts[b * 22 + 0] = curx; out_starts[b * 22 + 1] = cury; }
#pragma unroll
    for (int i = 0; i < 10; ++i) {
        float sx  = sm[b * 30 + i * 3 + 0];
        float sy  = sm[b * 30 + i * 3 + 1];
        float rot = tanhf(sm[b * 30 + i * 3 + 2]) * 3.14f;
        float c = cosf(rot), s = sinf(rot);
        float cx = bx0 * sx, cy = by0 * sy;
        if (j < 200) {
            float px = bx * sx, py = by * sy;
            float rx = c * (px - cx) - s * (py - cy) + cx;
            float ry = s * (px - cx) + c * (py - cy) + cy;
            size_t o = ((size_t)b * 2000 + i * 200 + j) * 2;
            out_traj[o + 0] = curx + rx;
            out_traj[o + 1] = cury + ry;
        }
        float pxL = bxL * sx, pyL = byL * sy;
        float exL = c * (pxL - cx) - s * (pyL - cy) + cx;
        float eyL = s * (pxL - cx) + c * (pyL - cy) + cy;
        curx += exL; cury += eyL;
        if (j == 0) {
            out_starts[b * 22 + (i + 1) * 2 + 0] = curx;
            out_starts[b * 22 + (i + 1) * 2 + 1] = cury;
        }
    }
}

// ---------------------------------------------------------------------------
// sampler: event-jump exact reimplementation of the reference scan.
// ---------------------------------------------------------------------------
__global__ __launch_bounds__(64)
void sample_kernel(const float* __restrict__ sl_in, const float* __restrict__ traj,
                   float* __restrict__ samp_out)
{
    __shared__ unsigned int maskb[32][63];
    __shared__ float ssl[32][10];
    int tid = threadIdx.x;
    for (int t = tid; t < 32 * 63; t += 64) ((unsigned int*)maskb)[t] = 0u;
    for (int t = tid; t < 32 * 10; t += 64) ((float*)ssl)[t] = sl_in[t];
    __syncthreads();
    if (tid >= 32) return;
    int b = tid;
    const float* tb = traj + (size_t)b * 4000;
    float* sp = samp_out + (size_t)b * 400;
    int out_n = 0;
    float last = 0.f, ntot = 0.f;
    float lim0 = ssl[b][0];
    float di = floorf(199.f / lim0);
    float ct0 = 0.f;
    if ((ntot < 200.f) && (ct0 < lim0) && (0.f - last == di)) {
        ntot += 1.f; ct0 += 1.f;
        maskb[b][0] |= 1u;
        sp[out_n * 2] = tb[0]; sp[out_n * 2 + 1] = tb[1]; ++out_n;
    }
    {
        float ndi = floorf((199.f - last) / (lim0 - ct0));
        if (di < ndi) di = ndi;
        if ((ntot < 200.f) && (ct0 < lim0) && (1.f - last == di)) {
            last = 1.f; ntot += 1.f; ct0 += 1.f;
            maskb[b][0] |= 2u;
            sp[out_n * 2] = tb[2]; sp[out_n * 2 + 1] = tb[3]; ++out_n;
        }
    }
    for (int seg = 0; seg < 10; ++seg) {
        float lim = ssl[b][seg];
        float ct = (seg == 0) ? ct0 : 0.f;
        float segbase = 200.f * seg;
        float segend = segbase + 199.f;
        float pos = (seg == 0) ? 2.f : segbase;
        float ndi = floorf((199.f - (last - segbase)) / (lim - ct));
        while ((ntot < 200.f) && (ct < lim)) {
            float fi = last + ndi;
            if (!(fi >= pos && fi <= segend)) break;
            int i = (int)fi;
            last = fi; ntot += 1.f; ct += 1.f;
            maskb[b][i >> 5] |= (1u << (i & 31));
            sp[out_n * 2] = tb[2 * i]; sp[out_n * 2 + 1] = tb[2 * i + 1]; ++out_n;
            pos = fi + 1.f;
            ndi = floorf((199.f - (last - segbase)) / (lim - ct));
        }
    }
    for (int i = 0; i < 2000 && out_n < 200; ++i) {
        if (!((maskb[b][i >> 5] >> (i & 31)) & 1u)) {
            sp[out_n * 2] = tb[2 * i]; sp[out_n * 2 + 1] = tb[2 * i + 1]; ++out_n;
        }
    }
}

// ---------------------------------------------------------------------------
extern "C" void kernel_launch(void* const* d_in, const int* in_sizes, int n_in,
                              void* d_out, int out_size, void* d_ws, size_t ws_size,
                              hipStream_t stream)
{
    const float* x    = (const float*)d_in[0];
    const float* w1   = (const float*)d_in[1];
    const float* b1   = (const float*)d_in[2];
    const float* w2   = (const float*)d_in[3];
    const float* b2   = (const float*)d_in[4];
    const float* w3   = (const float*)d_in[5];
    const float* b3   = (const float*)d_in[6];
    const float* w4   = (const float*)d_in[7];
    const float* b4   = (const float*)d_in[8];
    const float* fcw1 = (const float*)d_in[9];
    const float* fcb1 = (const float*)d_in[10];
    const float* fcw2 = (const float*)d_in[11];
    const float* fcb2 = (const float*)d_in[12];
    const float* wi   = (const float*)d_in[13];
    const float* bi   = (const float*)d_in[14];
    const float* wsw  = (const float*)d_in[15];
    const float* bs   = (const float*)d_in[16];
    const float* wr   = (const float*)d_in[17];
    const float* br   = (const float*)d_in[18];
    const float* base = (const float*)d_in[19];

    float* out = (float*)d_out;
    float* ws  = (float*)d_ws;

    float* p1   = ws + 0;        // 32x64x63x63   (8,128,512)
    float* p2   = ws + 8128512;  // 32x128x30x30  (3,686,400)
    float* p3   = ws + 0;        // 32x256x14x14  (reuses p1)
    float* feat = ws + 8128512;  // 32x512x6x6    (reuses p2)
    float* z1   = ws + 0;        // 32x2048       (reuses p3)
    float* z2   = ws + 65536;    // 32x2048
    float* ipos = ws + 131072;   // 32x2
    float* smod = ws + 131136;   // 32x30
    float* rlog = ws + 132096;   // 32x10
    float* slim = ws + 132416;   // 32x10

    float* out_samp   = out;            // 32*200*2 = 12800
    float* out_starts = out + 12800;    // 32*11*2  = 704
    float* out_ratio  = out + 13504;    // 32*10    = 320
    float* out_traj   = out + 13824;    // 32*2000*2 = 128000

    conv1_lds<<<4096, 256, 0, stream>>>(x, w1, b1, p1);
    conv_v9<64, 63, 30, 128, 4, 2><<<1024, 256, 0, stream>>>(p1, w2, b2, p2);
    conv_v9<128, 30, 14, 256, 2, 1><<<512, 256, 0, stream>>>(p2, w3, b3, p3);
    conv4_v3<<<1024, 256, 0, stream>>>(p3, w4, b4, feat);

    fc_big<<<256, 1024, 0, stream>>>(feat, fcw1, fcb1, z1, 18432, 2048, 1);
    fc_big<<<256, 1024, 0, stream>>>(z1, fcw2, fcb2, z2, 2048, 2048, 0);

    fc_two<<<1, 256, 0, stream>>>(z2, wi, bi, ipos, 2048, 2, 0);
    fc_two<<<15, 256, 0, stream>>>(z2, wsw, bs, smod, 2048, 30, 0);
    fc_two<<<5, 256, 0, stream>>>(z2, wr, br, rlog, 2048, 10, 0);

    post_kernel<<<1, 64, 0, stream>>>(rlog, out_ratio, slim);
    traj_kernel<<<32, 256, 0, stream>>>(base, ipos, smod, out_traj, out_starts);
    sample_kernel<<<1, 64, 0, stream>>>(slim, out_traj, out_samp);
}